// Round 8
// baseline (418.154 us; speedup 1.0000x reference)
//
#include <hip/hip_runtime.h>

#define N_NODES 50000
#define N_EDGES 800000
#define D 64
#define NUM_GRAPHS 512
#define FINAL_NEURON 128
#define SCAN_NB ((N_NODES + 255) / 256)   // 196 blocks

// ---------------- CSR build ----------------
__global__ void k_zero2(int* a, int* b, int n) {
    int i = blockIdx.x * blockDim.x + threadIdx.x;
    if (i < n) { a[i] = 0; b[i] = 0; }
}

__global__ void k_hist(const int* __restrict__ dst, int* cnt) {
    int e = blockIdx.x * blockDim.x + threadIdx.x;
    if (e < N_EDGES) atomicAdd(&cnt[dst[e]], 1);
}

// per-block sums of cnt; also emit dinv = rsqrt(cnt+1); also zero g (pool acc)
__global__ void k_blocksum(const int* __restrict__ cnt, int* __restrict__ bsum,
                           float* __restrict__ dinv, float* __restrict__ g) {
    __shared__ int sdata[256];
    int t = threadIdx.x;
    int i = blockIdx.x * 256 + t;
    int v = (i < N_NODES) ? cnt[i] : 0;
    if (i < N_NODES) dinv[i] = rsqrtf((float)v + 1.0f);
    if (i < NUM_GRAPHS * D) g[i] = 0.f;
    sdata[t] = v;
    __syncthreads();
    for (int s = 128; s > 0; s >>= 1) {
        if (t < s) sdata[t] += sdata[t + s];
        __syncthreads();
    }
    if (t == 0) bsum[blockIdx.x] = sdata[0];
}

__global__ void k_scanbsum(const int* __restrict__ bsum, int* __restrict__ boff) {
    __shared__ int buf[256];
    int t = threadIdx.x;
    int v = (t < SCAN_NB) ? bsum[t] : 0;
    buf[t] = v;
    __syncthreads();
    for (int off = 1; off < 256; off <<= 1) {
        int a = (t >= off) ? buf[t - off] : 0;
        __syncthreads();
        buf[t] += a;
        __syncthreads();
    }
    if (t < SCAN_NB) boff[t] = buf[t] - v;   // exclusive
}

__global__ void k_localscan(const int* __restrict__ cnt, const int* __restrict__ boff,
                            int* __restrict__ row) {
    __shared__ int buf[256];
    int t = threadIdx.x;
    int i = blockIdx.x * 256 + t;
    int v = (i < N_NODES) ? cnt[i] : 0;
    buf[t] = v;
    __syncthreads();
    for (int off = 1; off < 256; off <<= 1) {
        int a = (t >= off) ? buf[t - off] : 0;
        __syncthreads();
        buf[t] += a;
        __syncthreads();
    }
    if (i < N_NODES) row[i] = boff[blockIdx.x] + buf[t] - v;
    if (i == 0) row[N_NODES] = N_EDGES;
}

// place each edge: one packed 8B store {src, norm}; XCD-affinity sweep.
#define FILL_GROUP_BLOCKS 392
__global__ void k_fill(const int* __restrict__ src, const int* __restrict__ dst,
                       const int* __restrict__ row, int* cur,
                       const float* __restrict__ dinv,
                       int2* __restrict__ edge) {
    int rng = blockIdx.x & 7;
    int lo = rng * (N_NODES / 8);
    int hi = (rng == 7) ? N_NODES : lo + (N_NODES / 8);
    int stride = FILL_GROUP_BLOCKS * 256;
    for (int e = (blockIdx.x >> 3) * 256 + threadIdx.x; e < N_EDGES; e += stride) {
        int d = dst[e];
        if (d < lo || d >= hi) continue;
        int s = src[e];
        int pos = atomicAdd(&cur[d], 1);
        float nm = dinv[s] * dinv[d];
        int2 packed = {s, __float_as_int(nm)};
        edge[row[d] + pos] = packed;
    }
}

// ---------------- fused GCN layer: hout = relu((A_hat @ hin) @ W + b) ----------------
// Uses (A_hat h)W == A_hat(hW). Block = 32 nodes, 256 threads.
// Phase 1 (gather): thread t handles nodes base+(t>>4)*2 + {0,1}, col c=t&15
//   (one float4 per lane) -> aggregated rows land in LDS hs[32][68].
// Phase 2 (mini-gemm): thread computes 2 output rows x float4 from hs x Ws.
__global__ __launch_bounds__(256, 4)
void k_layer(const int* __restrict__ row, const int2* __restrict__ edge,
             const float* __restrict__ hin, const float* __restrict__ dinv,
             const float* __restrict__ W, const float* __restrict__ b,
             float* __restrict__ hout) {
    __shared__ float4 Ws4[D * 16];       // 16 KB
    __shared__ float  hs[32 * 68];       // 8.7 KB (stride 272 B = 17 x 16 B)
    int t = threadIdx.x;
    int c = t & 15;
    int rr = t >> 4;                     // 0..15
    int rt = rr * 2;
    int base = blockIdx.x * 32;

    const float4* W4 = (const float4*)W;
    for (int idx = t; idx < D * 16; idx += 256) Ws4[idx] = W4[idx];

    const float4* h4 = (const float4*)hin;
    #pragma unroll
    for (int p = 0; p < 2; ++p) {
        int n = base + rt + p;
        float4 acc = {0.f, 0.f, 0.f, 0.f};
        if (n < N_NODES) {
            int e = row[n], e1 = row[n + 1];
            for (; e + 2 <= e1; e += 2) {
                int2 ed0 = edge[e];
                int2 ed1 = edge[e + 1];
                float4 v0 = h4[(size_t)ed0.x * 16 + c];
                float4 v1 = h4[(size_t)ed1.x * 16 + c];
                float n0 = __int_as_float(ed0.y);
                float n1 = __int_as_float(ed1.y);
                acc.x += v0.x * n0 + v1.x * n1;
                acc.y += v0.y * n0 + v1.y * n1;
                acc.z += v0.z * n0 + v1.z * n1;
                acc.w += v0.w * n0 + v1.w * n1;
            }
            if (e < e1) {
                int2 ed = edge[e];
                float nm = __int_as_float(ed.y);
                float4 v = h4[(size_t)ed.x * 16 + c];
                acc.x += v.x * nm; acc.y += v.y * nm; acc.z += v.z * nm; acc.w += v.w * nm;
            }
            float di = dinv[n];
            float sc = di * di;
            float4 vs = h4[(size_t)n * 16 + c];
            acc.x += vs.x * sc; acc.y += vs.y * sc; acc.z += vs.z * sc; acc.w += vs.w * sc;
        }
        *(float4*)&hs[(rt + p) * 68 + c * 4] = acc;
    }
    __syncthreads();

    // mini-gemm: out[n][j] = sum_k hs[n][k] * W[k][j], rows rt, rt+1
    float4 acc0 = {0,0,0,0}, acc1 = {0,0,0,0};
    #pragma unroll 4
    for (int k = 0; k < D; ++k) {
        float a0 = hs[(rt + 0) * 68 + k];
        float a1 = hs[(rt + 1) * 68 + k];
        float4 w = Ws4[k * 16 + c];
        acc0.x += a0 * w.x; acc0.y += a0 * w.y; acc0.z += a0 * w.z; acc0.w += a0 * w.w;
        acc1.x += a1 * w.x; acc1.y += a1 * w.y; acc1.z += a1 * w.z; acc1.w += a1 * w.w;
    }
    float4 bb = ((const float4*)b)[c];
    float4 r0, r1;
    r0.x = fmaxf(acc0.x + bb.x, 0.f); r0.y = fmaxf(acc0.y + bb.y, 0.f);
    r0.z = fmaxf(acc0.z + bb.z, 0.f); r0.w = fmaxf(acc0.w + bb.w, 0.f);
    r1.x = fmaxf(acc1.x + bb.x, 0.f); r1.y = fmaxf(acc1.y + bb.y, 0.f);
    r1.z = fmaxf(acc1.z + bb.z, 0.f); r1.w = fmaxf(acc1.w + bb.w, 0.f);
    if (base + rt + 0 < N_NODES) ((float4*)hout)[(size_t)(base + rt + 0) * 16 + c] = r0;
    if (base + rt + 1 < N_NODES) ((float4*)hout)[(size_t)(base + rt + 1) * 16 + c] = r1;
}

// ---------------- pooling ----------------
__global__ void k_pool(const int* __restrict__ batch, const float* __restrict__ h,
                       float* g) {
    int tid = blockIdx.x * blockDim.x + threadIdx.x;
    int f = tid & 63;
    int n0 = (tid >> 6) * 8;
    if (n0 >= N_NODES) return;
    int n1 = n0 + 8; if (n1 > N_NODES) n1 = N_NODES;
    int curb = batch[n0];
    float acc = 0.f;
    for (int n = n0; n < n1; ++n) {
        int bb = batch[n];
        if (bb != curb) { atomicAdd(&g[curb * D + f], acc); acc = 0.f; curb = bb; }
        acc += h[(size_t)n * D + f];
    }
    atomicAdd(&g[curb * D + f], acc);
}

// ---------------- fused MLP ----------------
__global__ void k_mlp(const float* __restrict__ g, const float* __restrict__ W1,
                      const float* __restrict__ b1, const float* __restrict__ W2,
                      const float* __restrict__ b2, float* __restrict__ out) {
    __shared__ float red[FINAL_NEURON];
    int row = blockIdx.x;
    int j = threadIdx.x;
    float acc = 0.f;
    #pragma unroll
    for (int k = 0; k < D; ++k) acc += g[row * D + k] * W1[k * FINAL_NEURON + j];
    acc = fmaxf(acc + b1[j], 0.f);
    red[j] = acc * W2[j];
    __syncthreads();
    for (int s = 64; s > 0; s >>= 1) {
        if (j < s) red[j] += red[j + s];
        __syncthreads();
    }
    if (j == 0) out[row] = red[0] + b2[0];
}

extern "C" void kernel_launch(void* const* d_in, const int* in_sizes, int n_in,
                              void* d_out, int out_size, void* d_ws, size_t ws_size,
                              hipStream_t stream) {
    const float* x     = (const float*)d_in[0];
    const int*   ei    = (const int*)d_in[1];
    const int*   src   = ei;
    const int*   dst   = ei + N_EDGES;
    const int*   batch = (const int*)d_in[2];
    const float* W[5]  = {(const float*)d_in[3], (const float*)d_in[5], (const float*)d_in[7],
                          (const float*)d_in[9], (const float*)d_in[11]};
    const float* b[5]  = {(const float*)d_in[4], (const float*)d_in[6], (const float*)d_in[8],
                          (const float*)d_in[10], (const float*)d_in[12]};
    const float* fc1W  = (const float*)d_in[13];
    const float* fc1b  = (const float*)d_in[14];
    const float* fc2W  = (const float*)d_in[15];
    const float* fc2b  = (const float*)d_in[16];
    float* out = (float*)d_out;

    // ws layout: float4-accessed arrays first (16B aligned), ints last.
    int2*  edge  = (int2*)d_ws;                     // E int2
    float* hA    = (float*)(edge + N_EDGES);        // N*D
    float* hB    = hA + (size_t)N_NODES * D;        // N*D
    float* g     = hB + (size_t)N_NODES * D;        // G*D
    float* dinv  = g + NUM_GRAPHS * D;              // N
    int*   cnt   = (int*)(dinv + N_NODES);          // N
    int*   row   = cnt + N_NODES;                   // N+1
    int*   cur   = row + N_NODES + 1;               // N
    int*   bsum  = cur + N_NODES;                   // 256
    int*   boff  = bsum + 256;                      // 256

    // ---- CSR build ----
    k_zero2<<<(N_NODES + 255) / 256, 256, 0, stream>>>(cnt, cur, N_NODES);
    k_hist<<<(N_EDGES + 255) / 256, 256, 0, stream>>>(dst, cnt);
    k_blocksum<<<SCAN_NB, 256, 0, stream>>>(cnt, bsum, dinv, g);
    k_scanbsum<<<1, 256, 0, stream>>>(bsum, boff);
    k_localscan<<<SCAN_NB, 256, 0, stream>>>(cnt, boff, row);
    k_fill<<<FILL_GROUP_BLOCKS * 8, 256, 0, stream>>>(src, dst, row, cur, dinv, edge);

    // ---- 5 fused GCN layers (ping-pong hA/hB) ----
    const int NB = (N_NODES + 31) / 32;
    k_layer<<<NB, 256, 0, stream>>>(row, edge, x,  dinv, W[0], b[0], hA);
    k_layer<<<NB, 256, 0, stream>>>(row, edge, hA, dinv, W[1], b[1], hB);
    k_layer<<<NB, 256, 0, stream>>>(row, edge, hB, dinv, W[2], b[2], hA);
    k_layer<<<NB, 256, 0, stream>>>(row, edge, hA, dinv, W[3], b[3], hB);
    k_layer<<<NB, 256, 0, stream>>>(row, edge, hB, dinv, W[4], b[4], hA);

    // ---- readout + fused MLP ----
    k_pool<<<((N_NODES + 7) / 8 * 64 + 255) / 256, 256, 0, stream>>>(batch, hA, g);
    k_mlp<<<NUM_GRAPHS, FINAL_NEURON, 0, stream>>>(g, fc1W, fc1b, fc2W, fc2b, out);
}

// Round 9
// 334.692 us; speedup vs baseline: 1.2494x; 1.2494x over previous
//
#include <hip/hip_runtime.h>
#include <hip/hip_fp16.h>

#define N_NODES 50000
#define N_EDGES 800000
#define D 64
#define NUM_GRAPHS 512
#define FINAL_NEURON 128
#define SCAN_NB ((N_NODES + 255) / 256)   // 196 blocks

// ---------------- CSR build ----------------
__global__ void k_zero2(int* a, int* b, int n) {
    int i = blockIdx.x * blockDim.x + threadIdx.x;
    if (i < n) { a[i] = 0; b[i] = 0; }
}

__global__ void k_hist(const int* __restrict__ dst, int* cnt) {
    int e = blockIdx.x * blockDim.x + threadIdx.x;
    if (e < N_EDGES) atomicAdd(&cnt[dst[e]], 1);
}

// per-block sums of cnt; also emit dinv = rsqrt(cnt+1); also zero g (pool acc)
__global__ void k_blocksum(const int* __restrict__ cnt, int* __restrict__ bsum,
                           float* __restrict__ dinv, float* __restrict__ g) {
    __shared__ int sdata[256];
    int t = threadIdx.x;
    int i = blockIdx.x * 256 + t;
    int v = (i < N_NODES) ? cnt[i] : 0;
    if (i < N_NODES) dinv[i] = rsqrtf((float)v + 1.0f);
    if (i < NUM_GRAPHS * D) g[i] = 0.f;
    sdata[t] = v;
    __syncthreads();
    for (int s = 128; s > 0; s >>= 1) {
        if (t < s) sdata[t] += sdata[t + s];
        __syncthreads();
    }
    if (t == 0) bsum[blockIdx.x] = sdata[0];
}

__global__ void k_scanbsum(const int* __restrict__ bsum, int* __restrict__ boff) {
    __shared__ int buf[256];
    int t = threadIdx.x;
    int v = (t < SCAN_NB) ? bsum[t] : 0;
    buf[t] = v;
    __syncthreads();
    for (int off = 1; off < 256; off <<= 1) {
        int a = (t >= off) ? buf[t - off] : 0;
        __syncthreads();
        buf[t] += a;
        __syncthreads();
    }
    if (t < SCAN_NB) boff[t] = buf[t] - v;   // exclusive
}

__global__ void k_localscan(const int* __restrict__ cnt, const int* __restrict__ boff,
                            int* __restrict__ row) {
    __shared__ int buf[256];
    int t = threadIdx.x;
    int i = blockIdx.x * 256 + t;
    int v = (i < N_NODES) ? cnt[i] : 0;
    buf[t] = v;
    __syncthreads();
    for (int off = 1; off < 256; off <<= 1) {
        int a = (t >= off) ? buf[t - off] : 0;
        __syncthreads();
        buf[t] += a;
        __syncthreads();
    }
    if (i < N_NODES) row[i] = boff[blockIdx.x] + buf[t] - v;
    if (i == 0) row[N_NODES] = N_EDGES;
}

// place each edge: one packed 8B store {src, norm}; XCD-affinity sweep.
#define FILL_GROUP_BLOCKS 392
__global__ void k_fill(const int* __restrict__ src, const int* __restrict__ dst,
                       const int* __restrict__ row, int* cur,
                       const float* __restrict__ dinv,
                       int2* __restrict__ edge) {
    int rng = blockIdx.x & 7;
    int lo = rng * (N_NODES / 8);
    int hi = (rng == 7) ? N_NODES : lo + (N_NODES / 8);
    int stride = FILL_GROUP_BLOCKS * 256;
    for (int e = (blockIdx.x >> 3) * 256 + threadIdx.x; e < N_EDGES; e += stride) {
        int d = dst[e];
        if (d < lo || d >= hi) continue;
        int s = src[e];
        int pos = atomicAdd(&cur[d], 1);
        float nm = dinv[s] * dinv[d];
        int2 packed = {s, __float_as_int(nm)};
        edge[row[d] + pos] = packed;
    }
}

// ---------------- x (fp32) -> fp16 ----------------
__global__ void k_tohalf(const float* __restrict__ x, __half* __restrict__ xh) {
    int i = blockIdx.x * blockDim.x + threadIdx.x;   // half2 index
    if (i < N_NODES * D / 2) {
        float2 f = ((const float2*)x)[i];
        ((__half2*)xh)[i] = __floats2half2_rn(f.x, f.y);
    }
}

// ---------------- fused GCN layer: hout = relu((A_hat @ hin) @ W + b) ----------------
// h stored fp16 (halves gather traffic: 128B/row). Block = 32 nodes, 256 threads.
// Phase 1: 8 lanes per node, lane c8 = t&7 gathers one uint4 (8 halves),
//   accumulates fp32 -> aggregated rows to LDS hs[32][68] (fp32).
// Phase 2: mini-gemm vs W (fp32 LDS), bias+relu, pack to fp16.
__global__ __launch_bounds__(256, 6)
void k_layer(const int* __restrict__ row, const int2* __restrict__ edge,
             const __half* __restrict__ hin, const float* __restrict__ dinv,
             const float* __restrict__ W, const float* __restrict__ b,
             __half* __restrict__ hout) {
    __shared__ float4 Ws4[D * 16];       // 16 KB
    __shared__ float  hs[32 * 68];       // 8.7 KB (row stride 272 B = 17x16B)
    int t = threadIdx.x;
    int base = blockIdx.x * 32;

    const float4* W4 = (const float4*)W;
    for (int idx = t; idx < D * 16; idx += 256) Ws4[idx] = W4[idx];

    // ---- phase 1: gather ----
    {
        int c8 = t & 7;                  // 8-feature group
        int ln = t >> 3;                 // local node 0..31
        int n = base + ln;
        const uint4* h16 = (const uint4*)hin;   // row = 8 x uint4
        float4 a0 = {0,0,0,0}, a1 = {0,0,0,0};
        if (n < N_NODES) {
            int e = row[n], e1 = row[n + 1];
            for (; e + 2 <= e1; e += 2) {
                int2 ed0 = edge[e];
                int2 ed1 = edge[e + 1];
                uint4 u0 = h16[(size_t)ed0.x * 8 + c8];
                uint4 u1 = h16[(size_t)ed1.x * 8 + c8];
                float n0 = __int_as_float(ed0.y);
                float n1 = __int_as_float(ed1.y);
                float2 p;
                p = __half22float2(*(const __half2*)&u0.x); a0.x += p.x * n0; a0.y += p.y * n0;
                p = __half22float2(*(const __half2*)&u0.y); a0.z += p.x * n0; a0.w += p.y * n0;
                p = __half22float2(*(const __half2*)&u0.z); a1.x += p.x * n0; a1.y += p.y * n0;
                p = __half22float2(*(const __half2*)&u0.w); a1.z += p.x * n0; a1.w += p.y * n0;
                p = __half22float2(*(const __half2*)&u1.x); a0.x += p.x * n1; a0.y += p.y * n1;
                p = __half22float2(*(const __half2*)&u1.y); a0.z += p.x * n1; a0.w += p.y * n1;
                p = __half22float2(*(const __half2*)&u1.z); a1.x += p.x * n1; a1.y += p.y * n1;
                p = __half22float2(*(const __half2*)&u1.w); a1.z += p.x * n1; a1.w += p.y * n1;
            }
            if (e < e1) {
                int2 ed = edge[e];
                uint4 u = h16[(size_t)ed.x * 8 + c8];
                float nm = __int_as_float(ed.y);
                float2 p;
                p = __half22float2(*(const __half2*)&u.x); a0.x += p.x * nm; a0.y += p.y * nm;
                p = __half22float2(*(const __half2*)&u.y); a0.z += p.x * nm; a0.w += p.y * nm;
                p = __half22float2(*(const __half2*)&u.z); a1.x += p.x * nm; a1.y += p.y * nm;
                p = __half22float2(*(const __half2*)&u.w); a1.z += p.x * nm; a1.w += p.y * nm;
            }
            // self-loop
            float di = dinv[n];
            float sc = di * di;
            uint4 u = h16[(size_t)n * 8 + c8];
            float2 p;
            p = __half22float2(*(const __half2*)&u.x); a0.x += p.x * sc; a0.y += p.y * sc;
            p = __half22float2(*(const __half2*)&u.y); a0.z += p.x * sc; a0.w += p.y * sc;
            p = __half22float2(*(const __half2*)&u.z); a1.x += p.x * sc; a1.y += p.y * sc;
            p = __half22float2(*(const __half2*)&u.w); a1.z += p.x * sc; a1.w += p.y * sc;
        }
        *(float4*)&hs[ln * 68 + c8 * 8]     = a0;
        *(float4*)&hs[ln * 68 + c8 * 8 + 4] = a1;
    }
    __syncthreads();

    // ---- phase 2: mini-gemm, rows rt, rt+1; cols c*4..c*4+3 ----
    int c = t & 15;
    int rt = (t >> 4) * 2;
    float4 acc0 = {0,0,0,0}, acc1 = {0,0,0,0};
    #pragma unroll 4
    for (int k = 0; k < D; ++k) {
        float a0 = hs[(rt + 0) * 68 + k];
        float a1 = hs[(rt + 1) * 68 + k];
        float4 w = Ws4[k * 16 + c];
        acc0.x += a0 * w.x; acc0.y += a0 * w.y; acc0.z += a0 * w.z; acc0.w += a0 * w.w;
        acc1.x += a1 * w.x; acc1.y += a1 * w.y; acc1.z += a1 * w.z; acc1.w += a1 * w.w;
    }
    float4 bb = ((const float4*)b)[c];
    __half2 lo, hi;
    if (base + rt + 0 < N_NODES) {
        lo = __floats2half2_rn(fmaxf(acc0.x + bb.x, 0.f), fmaxf(acc0.y + bb.y, 0.f));
        hi = __floats2half2_rn(fmaxf(acc0.z + bb.z, 0.f), fmaxf(acc0.w + bb.w, 0.f));
        uint2 pk = {*(unsigned*)&lo, *(unsigned*)&hi};
        ((uint2*)hout)[(size_t)(base + rt + 0) * 16 + c] = pk;
    }
    if (base + rt + 1 < N_NODES) {
        lo = __floats2half2_rn(fmaxf(acc1.x + bb.x, 0.f), fmaxf(acc1.y + bb.y, 0.f));
        hi = __floats2half2_rn(fmaxf(acc1.z + bb.z, 0.f), fmaxf(acc1.w + bb.w, 0.f));
        uint2 pk = {*(unsigned*)&lo, *(unsigned*)&hi};
        ((uint2*)hout)[(size_t)(base + rt + 1) * 16 + c] = pk;
    }
}

// ---------------- pooling (fp16 h -> fp32 g) ----------------
__global__ void k_pool(const int* __restrict__ batch, const __half* __restrict__ h,
                       float* g) {
    int tid = blockIdx.x * blockDim.x + threadIdx.x;
    int f = tid & 63;
    int n0 = (tid >> 6) * 8;
    if (n0 >= N_NODES) return;
    int n1 = n0 + 8; if (n1 > N_NODES) n1 = N_NODES;
    int curb = batch[n0];
    float acc = 0.f;
    for (int n = n0; n < n1; ++n) {
        int bb = batch[n];
        if (bb != curb) { atomicAdd(&g[curb * D + f], acc); acc = 0.f; curb = bb; }
        acc += __half2float(h[(size_t)n * D + f]);
    }
    atomicAdd(&g[curb * D + f], acc);
}

// ---------------- fused MLP ----------------
__global__ void k_mlp(const float* __restrict__ g, const float* __restrict__ W1,
                      const float* __restrict__ b1, const float* __restrict__ W2,
                      const float* __restrict__ b2, float* __restrict__ out) {
    __shared__ float red[FINAL_NEURON];
    int row = blockIdx.x;
    int j = threadIdx.x;
    float acc = 0.f;
    #pragma unroll
    for (int k = 0; k < D; ++k) acc += g[row * D + k] * W1[k * FINAL_NEURON + j];
    acc = fmaxf(acc + b1[j], 0.f);
    red[j] = acc * W2[j];
    __syncthreads();
    for (int s = 64; s > 0; s >>= 1) {
        if (j < s) red[j] += red[j + s];
        __syncthreads();
    }
    if (j == 0) out[row] = red[0] + b2[0];
}

extern "C" void kernel_launch(void* const* d_in, const int* in_sizes, int n_in,
                              void* d_out, int out_size, void* d_ws, size_t ws_size,
                              hipStream_t stream) {
    const float* x     = (const float*)d_in[0];
    const int*   ei    = (const int*)d_in[1];
    const int*   src   = ei;
    const int*   dst   = ei + N_EDGES;
    const int*   batch = (const int*)d_in[2];
    const float* W[5]  = {(const float*)d_in[3], (const float*)d_in[5], (const float*)d_in[7],
                          (const float*)d_in[9], (const float*)d_in[11]};
    const float* b[5]  = {(const float*)d_in[4], (const float*)d_in[6], (const float*)d_in[8],
                          (const float*)d_in[10], (const float*)d_in[12]};
    const float* fc1W  = (const float*)d_in[13];
    const float* fc1b  = (const float*)d_in[14];
    const float* fc2W  = (const float*)d_in[15];
    const float* fc2b  = (const float*)d_in[16];
    float* out = (float*)d_out;

    // ws layout: 16B-aligned vector arrays first, ints last.
    int2*   edge = (int2*)d_ws;                       // E int2
    __half* xh   = (__half*)(edge + N_EDGES);         // N*D half (6.4 MB)
    __half* hA   = xh + (size_t)N_NODES * D;          // N*D half
    __half* hB   = hA + (size_t)N_NODES * D;          // N*D half
    float*  g    = (float*)(hB + (size_t)N_NODES * D);// G*D
    float*  dinv = g + NUM_GRAPHS * D;                // N
    int*    cnt  = (int*)(dinv + N_NODES);            // N
    int*    row  = cnt + N_NODES;                     // N+1
    int*    cur  = row + N_NODES + 1;                 // N
    int*    bsum = cur + N_NODES;                     // 256
    int*    boff = bsum + 256;                        // 256

    // ---- CSR build + x->fp16 ----
    k_zero2<<<(N_NODES + 255) / 256, 256, 0, stream>>>(cnt, cur, N_NODES);
    k_hist<<<(N_EDGES + 255) / 256, 256, 0, stream>>>(dst, cnt);
    k_tohalf<<<(N_NODES * D / 2 + 255) / 256, 256, 0, stream>>>(x, xh);
    k_blocksum<<<SCAN_NB, 256, 0, stream>>>(cnt, bsum, dinv, g);
    k_scanbsum<<<1, 256, 0, stream>>>(bsum, boff);
    k_localscan<<<SCAN_NB, 256, 0, stream>>>(cnt, boff, row);
    k_fill<<<FILL_GROUP_BLOCKS * 8, 256, 0, stream>>>(src, dst, row, cur, dinv, edge);

    // ---- 5 fused GCN layers (ping-pong) ----
    const int NB = (N_NODES + 31) / 32;
    k_layer<<<NB, 256, 0, stream>>>(row, edge, xh, dinv, W[0], b[0], hA);
    k_layer<<<NB, 256, 0, stream>>>(row, edge, hA, dinv, W[1], b[1], hB);
    k_layer<<<NB, 256, 0, stream>>>(row, edge, hB, dinv, W[2], b[2], hA);
    k_layer<<<NB, 256, 0, stream>>>(row, edge, hA, dinv, W[3], b[3], hB);
    k_layer<<<NB, 256, 0, stream>>>(row, edge, hB, dinv, W[4], b[4], hA);

    // ---- readout + fused MLP ----
    k_pool<<<((N_NODES + 7) / 8 * 64 + 255) / 256, 256, 0, stream>>>(batch, hA, g);
    k_mlp<<<NUM_GRAPHS, FINAL_NEURON, 0, stream>>>(g, fc1W, fc1b, fc2W, fc2b, out);
}